// Round 8
// baseline (235.431 us; speedup 1.0000x reference)
//
#include <hip/hip_runtime.h>
#include <math.h>

// VectorQuantizer: argmin_k ||x_n - c_k||^2, N=32768, K=8192, D=64, fp32.
// Round-14: NO LDS staging for B -- plain global loads straight to VGPRs.
//
// r7-r13 post-mortem: four different schedules (barriered, counted-vmcnt,
// barrier-free) all pin global_load_lds staging at 12-14 B/cy/CU (r7 12.1,
// r8 14.1, r12 13.5, r13 13.7) -- the LDS-DMA path itself is the wall
// (~1.7 B/cy/wave; limited per-wave DMA concurrency x ~200cy L2 latency).
// MFMA needs only 1550cy/body/CU of the measured 4800cy -> MfmaUtil 37%.
// In r13's wave-private structure B has ZERO cross-wave reuse, so LDS
// staging adds nothing: this round loads B fragments directly into VGPRs
// via plain global_load_dwordx4 (path measured 25-60 B/cy/CU, m13/m56),
// register double-buffered (static bA/bB sets, rule #20), barrier-free.
//  * Per wave per body: 8x 16B/lane loads (planes) + 1x 4B/lane (csq),
//    1KB/instr coalesced, L2-resident (bSwz = 2.1MB).
//  * Loop: LOADB(B,t+1); BODY(A,t); LOADB(A,t+2); BODY(B,t+1). Prefetch
//    flies under the ~800cy body; compiler inserts the vmcnt waits.
//  * Immediate epilogue (distP dropped, saves 32 VGPRs): acc-chain wait is
//    covered by the other wave on the SIMD (barrier-free slip).
//  * LDS = 16KB transient A-staging + 2KB reduction -> 18KB/block.
// Numerics identical to r13 (passed, absmax 0): 2-plane f16 split (plane1
// denormal-zeroed, plane2 pre-scaled 2^12), 3 products (A=h1g1 4-chain,
// B=h1g2'+h2'g1 8-chain), d = fmaf(-2, fmaf(B,2^-12,A), csq) [xsq omitted:
// per-row const, argmin-invariant], strict < ascending code, fkey-mapped
// u64 mins (negative-d safe) = first-occurrence.
// C/D layout (measured m74/m101): col=lane&31, row=(reg&3)+8*(reg>>2)+4*(lane>>5).

typedef __attribute__((ext_vector_type(8)))  _Float16 h8v;
typedef __attribute__((ext_vector_type(16))) float f16v;

constexpr int NROWS = 32768;
constexpr int KC    = 8192;
constexpr int DD    = 64;
constexpr int TPB   = 256;             // 4 waves, one 32-code group slice each
constexpr int PTPB  = 256;             // pre-kernel block size
constexpr int BROWS = 64;              // rows per block -> 512 blocks = 2/CU
constexpr int GUNIT = 4224;            // halves per group unit: 4096 planes + 128 csq-floats
constexpr int NBODY = 64;              // 256 groups / 4 waves

__device__ __forceinline__ void split2h(float v, _Float16& h1, _Float16& h2) {
  const float av = fabsf(v);
  _Float16 a = (_Float16)v;                  // RNE
  if (av < 6.1035156e-5f) a = (_Float16)0.f; // keep plane-1 out of f16 denormals
  h1 = a;
  h2 = (_Float16)((v - (float)a) * 4096.f);  // exact residual, scaled 2^12
}

// Monotone map: unsigned order of mapped bits == float order (handles negatives).
__device__ __forceinline__ unsigned fkey(float f) {
  const unsigned u = __float_as_uint(f);
  return u ^ (((unsigned)((int)u >> 31)) | 0x80000000u);
}

// Pre-kernel (128 blocks, 4 threads/code): split cb into frag-ordered group
// units [8KB planes | 256B csq x2-duplicated]. Chunk layout per group:
// chunk (p,kc) = 64 lanes x 8 f16, lane (h*32+l) = code l, k = kc*16+h*8+j.
// Unchanged from r13 (passed).
__global__ void vq_pre_kernel(const float* __restrict__ cb,
                              _Float16* __restrict__ bSwz) {
  const int gidx = blockIdx.x * PTPB + threadIdx.x;  // 0..32767
  const int code = gidx >> 2;
  const int kc4  = gidx & 3;                         // this thread's k-chunk
  const float* cp = cb + (size_t)code * DD + kc4 * 16;
  float v[16];
#pragma unroll
  for (int d = 0; d < 16; d += 4) {
    const float4 g = *(const float4*)(cp + d);
    v[d] = g.x; v[d + 1] = g.y; v[d + 2] = g.z; v[d + 3] = g.w;
  }
  float s = 0.f;
#pragma unroll
  for (int d = 0; d < 16; ++d) s = fmaf(v[d], v[d], s);
  s += __shfl_xor(s, 1, 64);
  s += __shfl_xor(s, 2, 64);
  _Float16 p1[16], p2[16];
#pragma unroll
  for (int d = 0; d < 16; ++d) split2h(v[d], p1[d], p2[d]);
  const int g = code >> 5, l = code & 31;
  _Float16* base = bSwz + (size_t)g * GUNIT;
#pragma unroll
  for (int p = 0; p < 2; ++p) {
    const _Float16* pl = p ? p2 : p1;
#pragma unroll
    for (int h = 0; h < 2; ++h) {
      h8v wv;
#pragma unroll
      for (int j = 0; j < 8; ++j) wv[j] = pl[h * 8 + j];
      *(h8v*)(base + (p * 4 + kc4) * 512 + (h * 32 + l) * 8) = wv;
    }
  }
  if (kc4 == 0) {
    float* cs2 = (float*)(base + 4096);
    cs2[l] = s; cs2[32 + l] = s;     // duplicated for lane-halves
  }
}

// Load one group's B fragments + csq straight into registers.
#define LOADB(P0, P1, CS, T)                                                  \
  {                                                                           \
    const _Float16* gs = bSwz + (size_t)((T) * 4 + w) * GUNIT + lane * 8;     \
    _Pragma("unroll")                                                         \
    for (int kc = 0; kc < 4; ++kc) {                                          \
      P0[kc] = *(const h8v*)(gs + kc * 512);                                  \
      P1[kc] = *(const h8v*)(gs + (4 + kc) * 512);                            \
    }                                                                         \
    CS = *(const float*)((const char*)(bSwz + (size_t)((T) * 4 + w) * GUNIT   \
                                       + 4096) + lane * 4);                   \
  }

// 24 MFMAs + immediate argmin epilogue for one tile.
#define BODY(P0, P1, CS, T)                                                   \
  {                                                                           \
    __builtin_amdgcn_s_setprio(1);                                            \
    f16v A0 = Z, B0v = Z, A1 = Z, B1v = Z;                                    \
    _Pragma("unroll")                                                         \
    for (int kc = 0; kc < 4; ++kc) {                                          \
      A0  = __builtin_amdgcn_mfma_f32_32x32x16_f16(afr[0][0][kc], P0[kc], A0,  0, 0, 0); \
      A1  = __builtin_amdgcn_mfma_f32_32x32x16_f16(afr[1][0][kc], P0[kc], A1,  0, 0, 0); \
      B0v = __builtin_amdgcn_mfma_f32_32x32x16_f16(afr[0][0][kc], P1[kc], B0v, 0, 0, 0); \
      B1v = __builtin_amdgcn_mfma_f32_32x32x16_f16(afr[1][0][kc], P1[kc], B1v, 0, 0, 0); \
    }                                                                         \
    _Pragma("unroll")                                                         \
    for (int kc = 0; kc < 4; ++kc) {                                          \
      B0v = __builtin_amdgcn_mfma_f32_32x32x16_f16(afr[0][1][kc], P0[kc], B0v, 0, 0, 0); \
      B1v = __builtin_amdgcn_mfma_f32_32x32x16_f16(afr[1][1][kc], P0[kc], B1v, 0, 0, 0); \
    }                                                                         \
    __builtin_amdgcn_s_setprio(0);                                            \
    const unsigned code = (unsigned)(((T) * 4 + w) * 32 + col);               \
    _Pragma("unroll")                                                         \
    for (int i = 0; i < 16; ++i) {                                            \
      const float d0 = fmaf(-2.f, fmaf(B0v[i], 2.44140625e-4f, A0[i]), CS);   \
      if (d0 < bestD[i])      { bestD[i] = d0;      bestC[i] = code; }        \
      const float d1 = fmaf(-2.f, fmaf(B1v[i], 2.44140625e-4f, A1[i]), CS);   \
      if (d1 < bestD[16 + i]) { bestD[16 + i] = d1; bestC[16 + i] = code; }   \
    }                                                                         \
  }

__global__ __launch_bounds__(TPB, 2)
void vq_mfma_kernel(const float* __restrict__ x, const _Float16* __restrict__ bSwz,
                    int* __restrict__ out) {
  __shared__ alignas(16) _Float16 ldsA[2 * BROWS * DD];       // 16384 B
  __shared__ alignas(16) unsigned long long ldsRed[BROWS][4]; // 2048 B

  const int tid  = threadIdx.x;
  const int lane = tid & 63;
  const int w    = tid >> 6;     // wave -> group slice (groups w, w+4, ...)
  const int half = lane >> 5;
  const int col  = lane & 31;
  const int blockRow = blockIdx.x * BROWS;

  // ---- Stage A: split 64 x-rows into 2 f16 planes, XOR-swizzled.
  {
    const int row = tid >> 2, dseg = (tid & 3) * 16;
    const float* xp = x + (size_t)(blockRow + row) * DD + dseg;
    float v[16];
#pragma unroll
    for (int d = 0; d < 16; d += 4) {
      const float4 g = *(const float4*)(xp + d);
      v[d] = g.x; v[d + 1] = g.y; v[d + 2] = g.z; v[d + 3] = g.w;
    }
    _Float16 qa[16], qb[16];
#pragma unroll
    for (int e = 0; e < 16; ++e) split2h(v[e], qa[e], qb[e]);
#pragma unroll
    for (int h2 = 0; h2 < 2; ++h2) {
      h8v a, b;
#pragma unroll
      for (int j = 0; j < 8; ++j) { a[j] = qa[h2 * 8 + j]; b[j] = qb[h2 * 8 + j]; }
      const int slot = (tid & 3) * 2 + h2;           // 16B slot (d/8)
      *(h8v*)&ldsA[(0 * 64 + row) * 64 + (slot ^ (row & 7)) * 8] = a;
      *(h8v*)&ldsA[(1 * 64 + row) * 64 + (slot ^ (row & 7)) * 8] = b;
    }
  }
  __syncthreads();

  // ---- A fragments resident: 2 stripes x 2 planes x 4 kchunks = 64 VGPR.
  h8v afr[2][2][4];
#pragma unroll
  for (int q = 0; q < 2; ++q)
#pragma unroll
    for (int p = 0; p < 2; ++p)
#pragma unroll
      for (int kc = 0; kc < 4; ++kc) {
        const int arow = q * 32 + col;
        const int slot = kc * 2 + half;
        afr[q][p][kc] =
            *(const h8v*)&ldsA[(p * 64 + arow) * 64 + ((slot ^ (arow & 7))) * 8];
      }

  float bestD[32];
  unsigned bestC[32];
#pragma unroll
  for (int i = 0; i < 32; ++i) { bestD[i] = INFINITY; bestC[i] = 0u; }

  const f16v Z = {0.f,0.f,0.f,0.f,0.f,0.f,0.f,0.f,0.f,0.f,0.f,0.f,0.f,0.f,0.f,0.f};

  // ---- Barrier-free main loop: register-double-buffered B (static sets).
  h8v bA0[4], bA1[4]; float csA;
  h8v bB0[4], bB1[4]; float csB;
  LOADB(bA0, bA1, csA, 0);
#pragma unroll 1
  for (int t = 0; t < NBODY; t += 2) {
    LOADB(bB0, bB1, csB, t + 1);
    BODY(bA0, bA1, csA, t);
    if (t + 2 < NBODY) LOADB(bA0, bA1, csA, t + 2);
    BODY(bB0, bB1, csB, t + 1);
  }

  // ---- Reduce across the 32 col-lanes (fkey u64 min: float order incl.
  // negatives, lowest code on exact ties), then across 4 waves via LDS.
  unsigned long long key[32];
#pragma unroll
  for (int i = 0; i < 32; ++i)
    key[i] = ((unsigned long long)fkey(bestD[i]) << 32) | bestC[i];
#pragma unroll
  for (int i = 0; i < 32; ++i) {
#pragma unroll
    for (int m = 1; m < 32; m <<= 1) {
      const unsigned long long o = __shfl_xor(key[i], m, 64);
      if (o < key[i]) key[i] = o;
    }
  }
  if (col == 0) {
#pragma unroll
    for (int i = 0; i < 32; ++i) {
      const int ii = i & 15, q = i >> 4;
      const int row = q * 32 + (ii & 3) + 8 * (ii >> 2) + 4 * half;
      ldsRed[row][w] = key[i];
    }
  }
  __syncthreads();
  if (tid < BROWS) {
    unsigned long long a = ldsRed[tid][0];
    const unsigned long long b = ldsRed[tid][1];
    const unsigned long long c = ldsRed[tid][2];
    const unsigned long long d = ldsRed[tid][3];
    if (b < a) a = b;
    if (c < a) a = c;
    if (d < a) a = d;
    out[blockRow + tid] = (int)(unsigned)(a & 0xFFFFFFFFull);
  }
}

extern "C" void kernel_launch(void* const* d_in, const int* in_sizes, int n_in,
                              void* d_out, int out_size, void* d_ws, size_t ws_size,
                              hipStream_t stream) {
  const float* x  = (const float*)d_in[0];   // [N, 64] fp32
  const float* cb = (const float*)d_in[1];   // [K, 64] fp32
  int* out = (int*)d_out;                    // [N] int32

  // ws: bSwz group units (256 x 8448 B = 2.06 MB)
  _Float16* bSwz = (_Float16*)d_ws;

  vq_pre_kernel<<<dim3(KC * 4 / PTPB), dim3(PTPB), 0, stream>>>(cb, bSwz);
  vq_mfma_kernel<<<dim3(NROWS / BROWS), dim3(TPB), 0, stream>>>(x, bSwz, out);
}

// Round 9
// 155.848 us; speedup vs baseline: 1.5106x; 1.5106x over previous
//
#include <hip/hip_runtime.h>
#include <math.h>

// VectorQuantizer: argmin_k ||x_n - c_k||^2, N=32768, K=8192, D=64, fp32.
// Round-15: 2-D grid (16 row-blocks x 16 code-blocks), codes RESIDENT in
// registers, x streamed through LDS with on-the-fly f16-plane split.
//
// r7-r14 post-mortem: all LDS-staging schedules pinned at ~1.8 B/cy/wave
// through global_load_lds (r13 13.7 B/cy/CU @8w; m97 22.2 @12w -- same
// per-wave constant). r12/r13 staged 4.2MB/CU -> 125us = measured wall.
// r14 (direct-to-reg B) spilled (live set ~290 VGPR): WRITE_SIZE 33MB.
// This round cuts staged bytes 11x and avoids the DMA path entirely:
//  * Grid 256 = 16 bn x 16 kb; block = 2048 rows x 512 codes; 8 waves;
//    wave holds its 64 codes as 16 h8v (64 VGPR) loaded ONCE (plain loads).
//  * x streamed in 16 subtiles of 128 rows: raw fp32 plain loads (issued a
//    body early) -> split2h VALU -> ds_write chunk-format (stride-516 pad:
//    writer 2-way bank = free; reader lane-linear b128). No global_load_lds.
//  * Operand roles swapped vs r13 (proven layouts are A/B-symmetric):
//    A=codes, B=x-rows -> C row(reg)=code, col(lane)=x-row. Per-lane argmin
//    over its 32 code-slots is PURE VALU in ascending-code order, then one
//    u64 shfl_xor(32) merges lane-halves, LDS merges 8 waves, and
//    atomicMin(u64 fkey<<32|code) into gkey[row] merges the 16 kb-blocks
//    (exact, order-independent, first-occurrence ties via low-bits code).
//  * Per body/CU: 768 MFMA (6200cy) vs 32KB ds_write + 32KB raw loads +
//    ~3500cy VALU -> MFMA-dominant. 2 barriers/body, 16 bodies.
// Numerics identical in kind to r7-r13 (all passed, absmax 0): 2-plane f16
// split (plane1 denormal-zeroed, plane2 pre-scaled 2^12), 3 products
// (accA=h1c*h1x 4-chain, accB=(h1c*h2x + h2c*h1x) 8-chain; the two 4-chains
// commuted vs r13 -- same reorder class), dist = fmaf(-2, fmaf(accB,2^-12,
// accA), csq), strict < ascending code, fkey u64 (negative-safe).
// C/D layout (measured m74/m101): col=lane&31, row=(reg&3)+8*(reg>>2)+4*(lane>>5).

typedef __attribute__((ext_vector_type(8)))  _Float16 h8v;
typedef __attribute__((ext_vector_type(16))) float f16v;

constexpr int NROWS = 32768;
constexpr int KC    = 8192;
constexpr int DD    = 64;
constexpr int TPB   = 512;            // 8 waves
constexpr int PTPB  = 256;            // pre/fin kernel block size
constexpr int NKB   = 16;             // code-block columns (512 codes each)
constexpr int RPB   = 2048;           // rows per block (16 row-blocks)
constexpr int SROWS = 128;            // rows per subtile
constexpr int NSUB  = RPB / SROWS;    // 16 bodies
constexpr int CH    = 516;            // padded chunk stride (halves; 512+4)

__device__ __forceinline__ void split2h(float v, _Float16& h1, _Float16& h2) {
  const float av = fabsf(v);
  _Float16 a = (_Float16)v;                  // RNE
  if (av < 6.1035156e-5f) a = (_Float16)0.f; // keep plane-1 out of f16 denormals
  h1 = a;
  h2 = (_Float16)((v - (float)a) * 4096.f);  // exact residual, scaled 2^12
}

// Monotone map: unsigned order of mapped bits == float order (handles negatives).
__device__ __forceinline__ unsigned fkey(float f) {
  const unsigned u = __float_as_uint(f);
  return u ^ (((unsigned)((int)u >> 31)) | 0x80000000u);
}

// Pre-kernel (128 blocks, 4 threads/code): split cb into frag-ordered groups
// (32 codes x 4096 halves; lane h*32+l = code l, k = kc*16+h*8+j), csq, and
// init gkey to +inf keys. Split/csq identical to r13 (passed).
__global__ void vq_pre_kernel(const float* __restrict__ cb,
                              _Float16* __restrict__ cbSwz,
                              float* __restrict__ csq,
                              unsigned long long* __restrict__ gkey) {
  const int gidx = blockIdx.x * PTPB + threadIdx.x;  // 0..32767
  gkey[gidx] = 0xFFFFFFFFFFFFFFFFull;                // one slot per row
  const int code = gidx >> 2;
  const int kc4  = gidx & 3;
  const float* cp = cb + (size_t)code * DD + kc4 * 16;
  float v[16];
#pragma unroll
  for (int d = 0; d < 16; d += 4) {
    const float4 g = *(const float4*)(cp + d);
    v[d] = g.x; v[d + 1] = g.y; v[d + 2] = g.z; v[d + 3] = g.w;
  }
  float s = 0.f;
#pragma unroll
  for (int d = 0; d < 16; ++d) s = fmaf(v[d], v[d], s);
  s += __shfl_xor(s, 1, 64);
  s += __shfl_xor(s, 2, 64);
  _Float16 p1[16], p2[16];
#pragma unroll
  for (int d = 0; d < 16; ++d) split2h(v[d], p1[d], p2[d]);
  const int g = code >> 5, l = code & 31;
  _Float16* base = cbSwz + (size_t)g * 4096;
#pragma unroll
  for (int p = 0; p < 2; ++p) {
    const _Float16* pl = p ? p2 : p1;
#pragma unroll
    for (int h = 0; h < 2; ++h) {
      h8v wv;
#pragma unroll
      for (int j = 0; j < 8; ++j) wv[j] = pl[h * 8 + j];
      *(h8v*)(base + (p * 4 + kc4) * 512 + (h * 32 + l) * 8) = wv;
    }
  }
  if (kc4 == 0) csq[code] = s;
}

// Split 16 raw floats (LR0..LR3) into 2 f16 planes and ds_write chunk-format.
#define SPLITWRITE(PAR)                                                        \
  {                                                                            \
    const float ff[16] = {LR0.x, LR0.y, LR0.z, LR0.w, LR1.x, LR1.y, LR1.z,     \
                          LR1.w, LR2.x, LR2.y, LR2.z, LR2.w, LR3.x, LR3.y,     \
                          LR3.z, LR3.w};                                       \
    _Pragma("unroll")                                                          \
    for (int h = 0; h < 2; ++h) {                                              \
      h8v p1v, p2v;                                                            \
      _Pragma("unroll")                                                        \
      for (int j = 0; j < 8; ++j) {                                            \
        _Float16 a_, b_;                                                       \
        split2h(ff[h * 8 + j], a_, b_);                                        \
        p1v[j] = a_; p2v[j] = b_;                                              \
      }                                                                        \
      *(h8v*)&bufX[PAR][((sg2 * 2 + 0) * 4 + skc) * CH + (h * 32 + sr31) * 8] = p1v; \
      *(h8v*)&bufX[PAR][((sg2 * 2 + 1) * 4 + skc) * CH + (h * 32 + sr31) * 8] = p2v; \
    }                                                                          \
  }

__global__ __launch_bounds__(TPB, 2)
void vq_mfma_kernel(const float* __restrict__ x, const _Float16* __restrict__ cbSwz,
                    const float* __restrict__ csq_g,
                    unsigned long long* __restrict__ gkey) {
  __shared__ alignas(16) _Float16 bufX[2][32 * CH];           // 66048 B
  __shared__ alignas(16) unsigned long long ldsRed[8][SROWS]; // 8192 B

  const int tid  = threadIdx.x;
  const int lane = tid & 63;
  const int w    = tid >> 6;
  const int half = lane >> 5;
  const int col  = lane & 31;
  const int kb   = blockIdx.x & (NKB - 1);
  const int bn   = blockIdx.x >> 4;
  const size_t nbase = (size_t)bn * RPB;

  // ---- Persistent code fragments: 2 stripes x 2 planes x 4 kc = 64 VGPR.
  h8v cbfr[2][2][4];
#pragma unroll
  for (int q = 0; q < 2; ++q)
#pragma unroll
    for (int p = 0; p < 2; ++p)
#pragma unroll
      for (int kc = 0; kc < 4; ++kc)
        cbfr[q][p][kc] = *(const h8v*)(cbSwz +
            (size_t)(kb * 16 + w * 2 + q) * 4096 + (p * 4 + kc) * 512 + lane * 8);

  // csq for this lane's 32 code-slots (uniform per half-wave; one-time).
  const int cbase = kb * 512 + w * 64 + 4 * half;
  float csq[2][16];
#pragma unroll
  for (int q = 0; q < 2; ++q)
#pragma unroll
    for (int i = 0; i < 16; ++i)
      csq[q][i] = csq_g[cbase + q * 32 + (i & 3) + 8 * (i >> 2)];

  // Splitter task ids: thread covers (row sr, k-chunk skc) = 16 floats.
  const int sr = tid >> 2, skc = tid & 3;
  const int sg2 = sr >> 5, sr31 = sr & 31;

  // ---- Prologue: stage subtile 0 into buf 0.
  float4 LR0, LR1, LR2, LR3;
  {
    const float* xp = x + (nbase + sr) * DD + skc * 16;
    LR0 = ((const float4*)xp)[0]; LR1 = ((const float4*)xp)[1];
    LR2 = ((const float4*)xp)[2]; LR3 = ((const float4*)xp)[3];
    SPLITWRITE(0);
  }
  asm volatile("s_waitcnt lgkmcnt(0)\n\ts_barrier" ::: "memory");

  const f16v Z = {0.f,0.f,0.f,0.f,0.f,0.f,0.f,0.f,0.f,0.f,0.f,0.f,0.f,0.f,0.f,0.f};

#pragma unroll 1
  for (int t = 0; t < NSUB; ++t) {
    const int par = t & 1;
    // Issue raw loads for subtile t+1 (consumed at body bottom; ~5000cy away).
    if (t + 1 < NSUB) {
      const float* xp = x + (nbase + (size_t)(t + 1) * SROWS + sr) * DD + skc * 16;
      LR0 = ((const float4*)xp)[0]; LR1 = ((const float4*)xp)[1];
      LR2 = ((const float4*)xp)[2]; LR3 = ((const float4*)xp)[3];
    }
    // 4 col-groups of 32 x-rows each.
#pragma unroll
    for (int cg = 0; cg < 4; ++cg) {
      h8v xfr[2][4];
#pragma unroll
      for (int p = 0; p < 2; ++p)
#pragma unroll
        for (int kc = 0; kc < 4; ++kc)
          xfr[p][kc] = *(const h8v*)&bufX[par][((cg * 2 + p) * 4 + kc) * CH + lane * 8];

      __builtin_amdgcn_s_setprio(1);
      f16v A0 = Z, B0 = Z, A1 = Z, B1 = Z;
#pragma unroll
      for (int kc = 0; kc < 4; ++kc) {
        A0 = __builtin_amdgcn_mfma_f32_32x32x16_f16(cbfr[0][0][kc], xfr[0][kc], A0, 0, 0, 0);
        A1 = __builtin_amdgcn_mfma_f32_32x32x16_f16(cbfr[1][0][kc], xfr[0][kc], A1, 0, 0, 0);
        B0 = __builtin_amdgcn_mfma_f32_32x32x16_f16(cbfr[0][0][kc], xfr[1][kc], B0, 0, 0, 0);
        B1 = __builtin_amdgcn_mfma_f32_32x32x16_f16(cbfr[1][0][kc], xfr[1][kc], B1, 0, 0, 0);
      }
#pragma unroll
      for (int kc = 0; kc < 4; ++kc) {
        B0 = __builtin_amdgcn_mfma_f32_32x32x16_f16(cbfr[0][1][kc], xfr[0][kc], B0, 0, 0, 0);
        B1 = __builtin_amdgcn_mfma_f32_32x32x16_f16(cbfr[1][1][kc], xfr[0][kc], B1, 0, 0, 0);
      }
      __builtin_amdgcn_s_setprio(0);

      // Per-lane argmin over its 32 code-slots (ascending code, strict <).
      float bd = INFINITY;
      unsigned bc = 0u;
#pragma unroll
      for (int i = 0; i < 16; ++i) {
        const float di = fmaf(-2.f, fmaf(B0[i], 2.44140625e-4f, A0[i]), csq[0][i]);
        if (di < bd) { bd = di; bc = (unsigned)(cbase + (i & 3) + 8 * (i >> 2)); }
      }
#pragma unroll
      for (int i = 0; i < 16; ++i) {
        const float di = fmaf(-2.f, fmaf(B1[i], 2.44140625e-4f, A1[i]), csq[1][i]);
        if (di < bd) { bd = di; bc = (unsigned)(cbase + 32 + (i & 3) + 8 * (i >> 2)); }
      }
      unsigned long long key = ((unsigned long long)fkey(bd) << 32) | bc;
      const unsigned long long o = __shfl_xor(key, 32, 64);
      if (o < key) key = o;
      if (half == 0) ldsRed[w][cg * 32 + col] = key;
    }
    // Split + write subtile t+1 into the other buffer.
    if (t + 1 < NSUB) SPLITWRITE(par ^ 1);
    asm volatile("s_waitcnt lgkmcnt(0)\n\ts_barrier" ::: "memory");
    // Merge 8 waves per row; publish via device-scope u64 atomicMin.
    if (tid < SROWS) {
      unsigned long long k0 = ldsRed[0][tid];
#pragma unroll
      for (int w2 = 1; w2 < 8; ++w2) {
        const unsigned long long o2 = ldsRed[w2][tid];
        if (o2 < k0) k0 = o2;
      }
      atomicMin(&gkey[nbase + (size_t)t * SROWS + tid], k0);
    }
    asm volatile("s_barrier" ::: "memory");
  }
}

// Final pass: key -> int32 index.
__global__ void vq_fin_kernel(const unsigned long long* __restrict__ gkey,
                              int* __restrict__ out) {
  const int n = blockIdx.x * PTPB + threadIdx.x;
  out[n] = (int)(unsigned)(gkey[n] & 0xFFFFFFFFull);
}

extern "C" void kernel_launch(void* const* d_in, const int* in_sizes, int n_in,
                              void* d_out, int out_size, void* d_ws, size_t ws_size,
                              hipStream_t stream) {
  const float* x  = (const float*)d_in[0];   // [N, 64] fp32
  const float* cb = (const float*)d_in[1];   // [K, 64] fp32
  int* out = (int*)d_out;                    // [N] int32

  // ws: cbSwz 2MB | csq 32KB | gkey 256KB  (total 2.33MB)
  _Float16* cbSwz = (_Float16*)d_ws;
  float* csq_g = (float*)((char*)d_ws + (size_t)KC * DD * 2 * 2);
  unsigned long long* gkey =
      (unsigned long long*)((char*)csq_g + (size_t)KC * 4);

  vq_pre_kernel<<<dim3(KC * 4 / PTPB), dim3(PTPB), 0, stream>>>(cb, cbSwz, csq_g, gkey);
  vq_mfma_kernel<<<dim3(NKB * (NROWS / RPB)), dim3(TPB), 0, stream>>>(
      x, cbSwz, csq_g, gkey);
  vq_fin_kernel<<<dim3(NROWS / PTPB), dim3(PTPB), 0, stream>>>(gkey, out);
}